// Round 2
// baseline (390.156 us; speedup 1.0000x reference)
//
#include <hip/hip_runtime.h>
#include <math.h>

#define L_ 8
#define D_ 128
#define B_ 8192
#define P_ 28
#define ALPHA_ 0.1f

typedef __attribute__((ext_vector_type(8))) short bf16x8;
typedef __attribute__((ext_vector_type(4))) float f32x4;

union BF8 { int4 i; bf16x8 h; };

__device__ __forceinline__ short f2bf(float f) {
    unsigned u = __float_as_uint(f);
    unsigned r = (u + 0x7fffu + ((u >> 16) & 1u)) >> 16;   // RNE
    return (short)(r & 0xffffu);
}
__device__ __forceinline__ float bf2f(unsigned short s) {
    return __uint_as_float(((unsigned)s) << 16);
}
// pack two floats -> two bf16 (RNE), a in low half
__device__ __forceinline__ unsigned rne2(float a, float b) {
    unsigned ua = __float_as_uint(a); ua += 0x7fffu + ((ua >> 16) & 1u);
    unsigned ub = __float_as_uint(b); ub += 0x7fffu + ((ub >> 16) & 1u);
    return __builtin_amdgcn_perm(ub, ua, 0x07060302);      // {b_hi16, a_hi16}
}

// K0: W[p][k][n] f32 -> WT[p][kb][n][kk] bf16  (kb=k/32, kk=k%32)
__global__ void transpose_w(const float* __restrict__ W1, const float* __restrict__ W2,
                            short* __restrict__ T1, short* __restrict__ T2) {
    const float* W = blockIdx.y ? W2 : W1;
    short* T = blockIdx.y ? T2 : T1;
    int bid = blockIdx.x;
    int et = bid & 7, kb = (bid >> 3) & 7, p = bid >> 6;
    __shared__ short tile[32][33];
    int tid = threadIdx.x;
    for (int s = tid; s < 1024; s += 256) {
        int kk = s >> 5, ee = s & 31;
        tile[kk][ee] = f2bf(W[((size_t)p * 256 + kb * 32 + kk) * 256 + et * 32 + ee]);
    }
    __syncthreads();
    for (int s = tid; s < 1024; s += 256) {
        int el = s >> 5, kk = s & 31;
        T[(((size_t)(p * 8 + kb)) * 256 + et * 32 + el) * 32 + kk] = tile[kk][el];
    }
}

// H/ENT blocked layout per pair (2,097,152 shorts):
// flat = tg*16384 + h1*8192 + c2*4096 + rt*2048 + rr*512 + ct*64 + mh*32 + q*8 + ml
// row = tg*64 + h1*32 + rt*16 + q*4 + rr ; col = c2*128 + ct*16 + mh*8 + ml

// G1: h = tanh(comb @ W1 + b1). Weights register-resident; no LDS; no barriers.
__launch_bounds__(256, 1)
__global__ void gemm1(const float* __restrict__ S, const short* __restrict__ W1T,
                      const float* __restrict__ b1, short* __restrict__ HE) {
    const int p = blockIdx.y;
    const int bx16 = blockIdx.x * 16;
    const int rb0 = blockIdx.x * 1024;
    const int lane = threadIdx.x & 63;
    const int w = threadIdx.x >> 6;
    const int h1 = w >> 1, c2 = w & 1;
    const int m = lane & 15, q = lane >> 4;

    int i = 0, base = 0;
    while (p >= base + (L_ - 1 - i)) { base += L_ - 1 - i; ++i; }
    const int j = i + 1 + (p - base);

    // W1 fragments, register resident: WF[ct][kb], lane m = col, q = k-subchunk
    bf16x8 WF[8][8];
    const short* wbase = W1T + (size_t)p * 8 * 256 * 32;
#pragma unroll
    for (int ct = 0; ct < 8; ++ct) {
        int n = c2 * 128 + ct * 16 + m;
#pragma unroll
        for (int kb = 0; kb < 8; ++kb)
            WF[ct][kb] = *(const bf16x8*)&wbase[((size_t)kb * 256 + n) * 32 + q * 8];
    }
    float bias[8];
#pragma unroll
    for (int ct = 0; ct < 8; ++ct) bias[ct] = b1[p * 256 + c2 * 128 + ct * 16 + m];

    const float* Si = S + (size_t)i * B_ * D_;
    const float* Sj = S + (size_t)j * B_ * D_;
    short* Hp = HE + (size_t)p * 2097152;

    for (int t = 0; t < 16; ++t) {
        const int row0 = rb0 + t * 64 + h1 * 32;
        // A fragments: rows row0+rt*16+m, k-chunk kb*32+q*8 (f32 -> bf16 RNE pack)
        bf16x8 AF[2][8];
#pragma unroll
        for (int rt = 0; rt < 2; ++rt) {
            const size_t ro_i = (size_t)(row0 + rt * 16 + m) * D_;
            const size_t ro_j = ro_i;
#pragma unroll
            for (int kb = 0; kb < 8; ++kb) {
                const float* src = (kb < 4) ? (Si + ro_i + kb * 32 + q * 8)
                                            : (Sj + ro_j + (kb - 4) * 32 + q * 8);
                float4 lo = *(const float4*)src;
                float4 hi = *(const float4*)(src + 4);
                BF8 u;
                u.i.x = rne2(lo.x, lo.y); u.i.y = rne2(lo.z, lo.w);
                u.i.z = rne2(hi.x, hi.y); u.i.w = rne2(hi.z, hi.w);
                AF[rt][kb] = u.h;
            }
        }
        f32x4 acc[2][8];
#pragma unroll
        for (int rt = 0; rt < 2; ++rt)
#pragma unroll
            for (int ct = 0; ct < 8; ++ct) acc[rt][ct] = (f32x4){0.f, 0.f, 0.f, 0.f};
#pragma unroll
        for (int kb = 0; kb < 8; ++kb)
#pragma unroll
            for (int ct = 0; ct < 8; ++ct)
#pragma unroll
                for (int rt = 0; rt < 2; ++rt)
                    acc[rt][ct] = __builtin_amdgcn_mfma_f32_16x16x32_bf16(
                        AF[rt][kb], WF[ct][kb], acc[rt][ct], 0, 0, 0);
        // epilogue: tanh(x+bias) -> blocked store (64 lanes x 2B = 128 B contiguous/inst)
        const size_t sb = (size_t)(bx16 + t) * 16384 + h1 * 8192 + c2 * 4096
                        + (m >> 3) * 32 + q * 8 + (m & 7);
#pragma unroll
        for (int rt = 0; rt < 2; ++rt)
#pragma unroll
            for (int rr = 0; rr < 4; ++rr) {
                const size_t rbse = sb + rt * 2048 + rr * 512;
#pragma unroll
                for (int ct = 0; ct < 8; ++ct) {
                    float x = acc[rt][ct][rr] + bias[ct];
                    float e = exp2f(x * 2.885390081777927f);        // e^{2x}
                    float th = 1.f - 2.f * __builtin_amdgcn_rcpf(e + 1.f);
                    Hp[rbse + ct * 64] = f2bf(th);
                }
            }
    }
}

// G2: ent = sigmoid(es) * (h @ W2 + b2), in-place over H (barrier between read & write)
__launch_bounds__(256, 1)
__global__ void gemm2(const float* __restrict__ ES, const short* __restrict__ W2T,
                      const float* __restrict__ b2, short* __restrict__ HE) {
    const int p = blockIdx.y;
    const int bx16 = blockIdx.x * 16;
    const int lane = threadIdx.x & 63;
    const int w = threadIdx.x >> 6;
    const int h1 = w >> 1, c2 = w & 1;
    const int m = lane & 15, q = lane >> 4;

    int i = 0, base = 0;
    while (p >= base + (L_ - 1 - i)) { base += L_ - 1 - i; ++i; }
    const int j = i + 1 + (p - base);
    const float es = ES[i * L_ + j];
    const float st = 1.f / (1.f + expf(-es));

    bf16x8 WF[8][8];
    const short* wbase = W2T + (size_t)p * 8 * 256 * 32;
#pragma unroll
    for (int ct = 0; ct < 8; ++ct) {
        int n = c2 * 128 + ct * 16 + m;
#pragma unroll
        for (int kb = 0; kb < 8; ++kb)
            WF[ct][kb] = *(const bf16x8*)&wbase[((size_t)kb * 256 + n) * 32 + q * 8];
    }
    float bias[8];
#pragma unroll
    for (int ct = 0; ct < 8; ++ct) bias[ct] = b2[p * 256 + c2 * 128 + ct * 16 + m];

    short* Hp = HE + (size_t)p * 2097152;
    // per-lane part of A-gather offset: rs*512 + qs*8 (+ q*32 from col bits)
    const int laneoff = (m & 3) * 512 + (m >> 2) * 8 + q * 32;

    for (int t = 0; t < 16; ++t) {
        const size_t tb = (size_t)(bx16 + t) * 16384 + h1 * 8192;
        bf16x8 AF[2][8];
#pragma unroll
        for (int rt = 0; rt < 2; ++rt)
#pragma unroll
            for (int kb = 0; kb < 8; ++kb)
                AF[rt][kb] = *(const bf16x8*)&Hp[tb + rt * 2048 + (kb >> 2) * 4096
                                                + (kb & 3) * 128 + laneoff];
        __syncthreads();   // all waves done reading tile before any in-place write
        f32x4 acc[2][8];
#pragma unroll
        for (int rt = 0; rt < 2; ++rt)
#pragma unroll
            for (int ct = 0; ct < 8; ++ct) acc[rt][ct] = (f32x4){0.f, 0.f, 0.f, 0.f};
#pragma unroll
        for (int kb = 0; kb < 8; ++kb)
#pragma unroll
            for (int ct = 0; ct < 8; ++ct)
#pragma unroll
                for (int rt = 0; rt < 2; ++rt)
                    acc[rt][ct] = __builtin_amdgcn_mfma_f32_16x16x32_bf16(
                        AF[rt][kb], WF[ct][kb], acc[rt][ct], 0, 0, 0);
        const size_t sb = (size_t)(bx16 + t) * 16384 + h1 * 8192 + c2 * 4096
                        + (m >> 3) * 32 + q * 8 + (m & 7);
#pragma unroll
        for (int rt = 0; rt < 2; ++rt)
#pragma unroll
            for (int rr = 0; rr < 4; ++rr) {
                const size_t rbse = sb + rt * 2048 + rr * 512;
#pragma unroll
                for (int ct = 0; ct < 8; ++ct)
                    Hp[rbse + ct * 64] = f2bf(st * (acc[rt][ct][rr] + bias[ct]));
            }
    }
}

// finalize: u <- u + alpha*(ent_part - u) in global pair order.
// wave = (k, tg, h1, rt, rs); lane = (qs, ch): each pair-read = contiguous 1 KB.
__global__ void finalize(const float* __restrict__ S, const short* __restrict__ ENT,
                         float* __restrict__ OUT) {
    int idx = blockIdx.x * 256 + threadIdx.x;
    int lane = idx & 63;
    int wv = idx >> 6;                 // 16384 waves
    int k = wv >> 11;                  // 2048 waves per layer
    int wid = wv & 2047;
    int tg = wid >> 4, h1 = (wid >> 3) & 1, rt = (wid >> 2) & 1, rs = wid & 3;
    int qs = lane >> 4, ch = lane & 15;
    int b = tg * 64 + h1 * 32 + rt * 16 + qs * 4 + rs;
    int d0 = ch * 8;
    size_t sOff = ((size_t)k * B_ + b) * D_ + d0;
    float4 u0 = *(const float4*)&S[sOff];
    float4 u1 = *(const float4*)&S[sOff + 4];
    float u[8] = {u0.x, u0.y, u0.z, u0.w, u1.x, u1.y, u1.z, u1.w};
    const size_t rowpart = (size_t)tg * 16384 + h1 * 8192 + rt * 2048 + rs * 512 + qs * 8;
    int p = 0;
#pragma unroll
    for (int i2 = 0; i2 < L_; ++i2) {
#pragma unroll
        for (int j2 = i2 + 1; j2 < L_; ++j2) {
            if (i2 == k || j2 == k) {
                int side = (i2 == k) ? 0 : 1;
                const short* e = ENT + (size_t)p * 2097152 + rowpart + side * 4096 + d0 * 4;
                ushort4 a = *(const ushort4*)e;
                ushort4 c = *(const ushort4*)(e + 4);
                u[0] += ALPHA_ * (bf2f(a.x) - u[0]);
                u[1] += ALPHA_ * (bf2f(a.y) - u[1]);
                u[2] += ALPHA_ * (bf2f(a.z) - u[2]);
                u[3] += ALPHA_ * (bf2f(a.w) - u[3]);
                u[4] += ALPHA_ * (bf2f(c.x) - u[4]);
                u[5] += ALPHA_ * (bf2f(c.y) - u[5]);
                u[6] += ALPHA_ * (bf2f(c.z) - u[6]);
                u[7] += ALPHA_ * (bf2f(c.w) - u[7]);
            }
            ++p;
        }
    }
    *(float4*)&OUT[sOff]     = (float4){u[0], u[1], u[2], u[3]};
    *(float4*)&OUT[sOff + 4] = (float4){u[4], u[5], u[6], u[7]};
}

// measures are analytically constant (lam1 == 1 after normalize):
// (127+127-255) * 1e-12 * (-ln 1e-12) = -2.7631021115928547e-11
__global__ void fill_meas(float* __restrict__ M) {
    int t = blockIdx.x * 256 + threadIdx.x;
    if (t < P_ * B_) M[t] = -2.7631021115928547e-11f;
}

extern "C" void kernel_launch(void* const* d_in, const int* in_sizes, int n_in,
                              void* d_out, int out_size, void* d_ws, size_t ws_size,
                              hipStream_t stream) {
    const float* S  = (const float*)d_in[0];
    const float* ES = (const float*)d_in[1];
    const float* W1 = (const float*)d_in[2];
    const float* b1 = (const float*)d_in[3];
    const float* W2 = (const float*)d_in[4];
    const float* b2 = (const float*)d_in[5];

    short* HE    = (short*)d_ws;                         // 28*2097152 shorts = 117.4 MB (H, then ENT in-place)
    short* wsW1T = HE + (size_t)P_ * 2097152;            // 3.67 MB
    short* wsW2T = wsW1T + (size_t)P_ * 8 * 256 * 32;    // 3.67 MB   (total 124.8 MB, same as R1)

    float* OUT  = (float*)d_out;                         // updated [L,B,D]
    float* MEAS = OUT + (size_t)L_ * B_ * D_;            // measures [P,B]

    transpose_w<<<dim3(P_ * 64, 2), 256, 0, stream>>>(W1, W2, wsW1T, wsW2T);
    gemm1<<<dim3(8, P_), 256, 0, stream>>>(S, wsW1T, b1, HE);
    gemm2<<<dim3(8, P_), 256, 0, stream>>>(ES, wsW2T, b2, HE);
    finalize<<<dim3(4096), 256, 0, stream>>>(S, HE, OUT);
    fill_meas<<<dim3(896), 256, 0, stream>>>(MEAS);
}

// Round 3
// 384.830 us; speedup vs baseline: 1.0138x; 1.0138x over previous
//
#include <hip/hip_runtime.h>
#include <math.h>

#define L_ 8
#define D_ 128
#define B_ 8192
#define P_ 28
#define ALPHA_ 0.1f

typedef __attribute__((ext_vector_type(8))) short bf16x8;
typedef __attribute__((ext_vector_type(4))) float f32x4;
union BF8 { int4 i; bf16x8 h; short s[8]; };

__device__ __forceinline__ short f2bf(float f) {
    unsigned u = __float_as_uint(f);
    unsigned r = (u + 0x7fffu + ((u >> 16) & 1u)) >> 16;   // RNE
    return (short)(r & 0xffffu);
}
__device__ __forceinline__ float bf2f(unsigned short s) {
    return __uint_as_float(((unsigned)s) << 16);
}
__device__ __forceinline__ unsigned rne2(float a, float b) {
    unsigned ua = __float_as_uint(a); ua += 0x7fffu + ((ua >> 16) & 1u);
    unsigned ub = __float_as_uint(b); ub += 0x7fffu + ((ub >> 16) & 1u);
    return __builtin_amdgcn_perm(ub, ua, 0x07060302);      // {b_hi16, a_hi16}
}

typedef const unsigned int __attribute__((address_space(1)))* gas_t;
typedef unsigned int __attribute__((address_space(3)))* las_t;

// stage one 16KB weight k-block (256 n x 32 kk bf16, contiguous) into LDS.
// wave w stages its 4KB quarter: 4 x global_load_lds_dwordx4.
__device__ __forceinline__ void stage_w(const short* g, short* l, int w, int lane) {
#pragma unroll
    for (int r = 0; r < 4; ++r) {
        int u0 = w * 256 + r * 64;   // 16B-unit index of lane 0
        __builtin_amdgcn_global_load_lds((gas_t)(const void*)(g + (size_t)(u0 + lane) * 8),
                                         (las_t)(void*)(l + (size_t)u0 * 8), 16, 0, 0);
    }
}

// K0: W[p][k][n] f32 -> WT[p][kb][n][kk] bf16  (kb=k/32, kk=k%32)
__global__ void transpose_w(const float* __restrict__ W1, const float* __restrict__ W2,
                            short* __restrict__ T1, short* __restrict__ T2) {
    const float* W = blockIdx.y ? W2 : W1;
    short* T = blockIdx.y ? T2 : T1;
    int bid = blockIdx.x;
    int et = bid & 7, kb = (bid >> 3) & 7, p = bid >> 6;
    __shared__ short tile[32][33];
    int tid = threadIdx.x;
    for (int s = tid; s < 1024; s += 256) {
        int kk = s >> 5, ee = s & 31;
        tile[kk][ee] = f2bf(W[((size_t)p * 256 + kb * 32 + kk) * 256 + et * 32 + ee]);
    }
    __syncthreads();
    for (int s = tid; s < 1024; s += 256) {
        int el = s >> 5, kk = s & 31;
        T[(((size_t)(p * 8 + kb)) * 256 + et * 32 + el) * 32 + kk] = tile[kk][el];
    }
}

// ENT fragment-blocked layout (shorts), total P*512*8*512 = P*2097152:
// addr = ((p*512 + rg)*8 + cp)*512 + lane*8 + tsel*4 + rr
// where row = rg*16 + (lane>>4)*4 + rr ; col = cp*32 + tsel*16 + (lane&15)

// Fused per-pair MLP: GEMM1(comb@W1,tanh) -> LDS -> GEMM2(h@W2,scale) -> ENT.
// Block: 128 rows x 1 pair. 4 waves, each 32 rows x 256 cols. Weights dbuf'd
// through LDS via global_load_lds; A-operands never touch a barrier.
__launch_bounds__(256, 1)
__global__ void pair_mlp(const float* __restrict__ S, const float* __restrict__ ES,
                         const short* __restrict__ W1T, const float* __restrict__ b1,
                         const short* __restrict__ W2T, const float* __restrict__ b2,
                         short* __restrict__ ENT) {
    __shared__ short Wbuf[2][8192];     // 2 x 16KB weight k-block (no pad: global_load_lds)
    __shared__ short Hsh[4][32 * 264];  // wave-private H slice, padded stride 264
    const int p = blockIdx.y;
    const int rb0 = blockIdx.x * 128;
    const int tid = threadIdx.x;
    const int lane = tid & 63, w = tid >> 6;
    const int m = lane & 15, q = lane >> 4;

    int i = 0, base = 0;
    while (p >= base + (L_ - 1 - i)) { base += L_ - 1 - i; ++i; }
    const int j = i + 1 + (p - base);

    const short* W1p = W1T + (size_t)p * 65536;
    const short* W2p = W2T + (size_t)p * 65536;

    stage_w(W1p, Wbuf[0], w, lane);     // prefetch W1 kb=0

    // A fragments (GEMM1) straight from global f32, RNE-packed to bf16
    const int rw = rb0 + w * 32;
    const float* Si = S + (size_t)i * B_ * D_;
    const float* Sj = S + (size_t)j * B_ * D_;
    bf16x8 AF[2][8];
#pragma unroll
    for (int rt = 0; rt < 2; ++rt) {
        const size_t ro = (size_t)(rw + rt * 16 + m) * D_;
#pragma unroll
        for (int kb = 0; kb < 8; ++kb) {
            const float* src = (kb < 4) ? (Si + ro + kb * 32 + q * 8)
                                        : (Sj + ro + (kb - 4) * 32 + q * 8);
            float4 lo = *(const float4*)src;
            float4 hi = *(const float4*)(src + 4);
            BF8 u;
            u.i.x = rne2(lo.x, lo.y); u.i.y = rne2(lo.z, lo.w);
            u.i.z = rne2(hi.x, hi.y); u.i.w = rne2(hi.z, hi.w);
            AF[rt][kb] = u.h;
        }
    }
    float bias1[16];
#pragma unroll
    for (int ct = 0; ct < 16; ++ct) bias1[ct] = b1[p * 256 + ct * 16 + m];

    f32x4 acc[2][16];
#pragma unroll
    for (int rt = 0; rt < 2; ++rt)
#pragma unroll
        for (int ct = 0; ct < 16; ++ct) acc[rt][ct] = (f32x4){0.f, 0.f, 0.f, 0.f};

    // ---- GEMM1: one barrier per k-block; prefetch has full MFMA phase to land ----
#pragma unroll
    for (int kb = 0; kb < 8; ++kb) {
        __syncthreads();
        const short* nxt = (kb < 7) ? (W1p + (size_t)(kb + 1) * 8192) : W2p;
        stage_w(nxt, Wbuf[(kb + 1) & 1], w, lane);
        const short* wb = Wbuf[kb & 1];
#pragma unroll
        for (int ct = 0; ct < 16; ++ct) {
            bf16x8 bfb = *(const bf16x8*)&wb[(ct * 16 + m) * 32 + q * 8];
#pragma unroll
            for (int rt = 0; rt < 2; ++rt)
                acc[rt][ct] = __builtin_amdgcn_mfma_f32_16x16x32_bf16(AF[rt][kb], bfb, acc[rt][ct], 0, 0, 0);
        }
    }

    // epilogue1: h = tanh(x + b1) -> wave-private LDS (no barrier needed)
    short* Hw = Hsh[w];
#pragma unroll
    for (int ct = 0; ct < 16; ++ct) {
        int col = ct * 16 + m;
#pragma unroll
        for (int rt = 0; rt < 2; ++rt)
#pragma unroll
            for (int rr = 0; rr < 4; ++rr) {
                float x = acc[rt][ct][rr] + bias1[ct];
                float e = exp2f(x * 2.885390081777927f);            // e^{2x}
                Hw[(rt * 16 + q * 4 + rr) * 264 + col] = f2bf(1.f - 2.f * __builtin_amdgcn_rcpf(e + 1.f));
            }
    }
    bf16x8 AF2[2][8];
#pragma unroll
    for (int rt = 0; rt < 2; ++rt)
#pragma unroll
        for (int kb = 0; kb < 8; ++kb)
            AF2[rt][kb] = *(const bf16x8*)&Hw[(rt * 16 + m) * 264 + kb * 32 + q * 8];

    float bias2[16];
#pragma unroll
    for (int ct = 0; ct < 16; ++ct) bias2[ct] = b2[p * 256 + ct * 16 + m];
#pragma unroll
    for (int rt = 0; rt < 2; ++rt)
#pragma unroll
        for (int ct = 0; ct < 16; ++ct) acc[rt][ct] = (f32x4){0.f, 0.f, 0.f, 0.f};

    // ---- GEMM2 ----
#pragma unroll
    for (int kb = 0; kb < 8; ++kb) {
        __syncthreads();
        if (kb < 7) stage_w(W2p + (size_t)(kb + 1) * 8192, Wbuf[(kb + 1) & 1], w, lane);
        const short* wb = Wbuf[kb & 1];
#pragma unroll
        for (int ct = 0; ct < 16; ++ct) {
            bf16x8 bfb = *(const bf16x8*)&wb[(ct * 16 + m) * 32 + q * 8];
#pragma unroll
            for (int rt = 0; rt < 2; ++rt)
                acc[rt][ct] = __builtin_amdgcn_mfma_f32_16x16x32_bf16(AF2[rt][kb], bfb, acc[rt][ct], 0, 0, 0);
        }
    }

    // epilogue2: ent = sigmoid(es)*(x + b2), fragment-blocked dwordx4 stores (1KB/inst)
    const float es = ES[i * L_ + j];
    const float st = 1.f / (1.f + expf(-es));
#pragma unroll
    for (int rt = 0; rt < 2; ++rt) {
        const int rg = (rb0 >> 4) + w * 2 + rt;
#pragma unroll
        for (int cp = 0; cp < 8; ++cp) {
            BF8 u;
#pragma unroll
            for (int ts = 0; ts < 2; ++ts)
#pragma unroll
                for (int rr = 0; rr < 4; ++rr)
                    u.s[ts * 4 + rr] = f2bf(st * (acc[rt][cp * 2 + ts][rr] + bias2[cp * 2 + ts]));
            *(int4*)&ENT[(((size_t)p * 512 + rg) * 8 + cp) * 512 + lane * 8] = u.i;
        }
    }
}

// finalize: u <- u + alpha*(ent_part - u) in global pair order.
// cp/tsel/lp0/rr are per-thread constants -> 8 imm-offset u16 loads per pair.
__global__ void finalize(const float* __restrict__ S, const short* __restrict__ ENT,
                         float* __restrict__ OUT) {
    int idx = blockIdx.x * 256 + threadIdx.x;
    int k = idx >> 17;                  // B*D/8 = 131072 threads per layer
    int rem = idx & 131071;
    int b = rem >> 4;
    int d0 = (rem & 15) * 8;
    size_t sOff = ((size_t)k * B_ + b) * D_ + d0;
    float4 u0 = *(const float4*)&S[sOff];
    float4 u1 = *(const float4*)&S[sOff + 4];
    float u[8] = {u0.x, u0.y, u0.z, u0.w, u1.x, u1.y, u1.z, u1.w};
    const int rg = b >> 4;
    const int cpo = d0 >> 5;            // constant across dj (d0%16 in {0,8}, dj<8)
    const int tsel = (d0 >> 4) & 1;
    const int lp0 = ((b & 15) >> 2) * 16 + (d0 & 15);
    const int rr = b & 3;
    int p = 0;
#pragma unroll
    for (int i2 = 0; i2 < L_; ++i2) {
#pragma unroll
        for (int j2 = i2 + 1; j2 < L_; ++j2) {
            if (i2 == k || j2 == k) {
                int side = (i2 == k) ? 0 : 4;
                const unsigned short* e = (const unsigned short*)ENT
                    + (((size_t)p * 512 + rg) * 8 + side + cpo) * 512 + lp0 * 8 + tsel * 4 + rr;
#pragma unroll
                for (int dj = 0; dj < 8; ++dj)
                    u[dj] += ALPHA_ * (bf2f(e[dj * 8]) - u[dj]);
            }
            ++p;
        }
    }
    *(float4*)&OUT[sOff]     = (float4){u[0], u[1], u[2], u[3]};
    *(float4*)&OUT[sOff + 4] = (float4){u[4], u[5], u[6], u[7]};
}

// measures are analytically constant (lam1 == 1 after normalize):
// (127+127-255)*1e-12*(-ln 1e-12) = -2.7631021115928547e-11
__global__ void fill_meas(float* __restrict__ M) {
    int t = blockIdx.x * 256 + threadIdx.x;
    if (t < P_ * B_) M[t] = -2.7631021115928547e-11f;
}

extern "C" void kernel_launch(void* const* d_in, const int* in_sizes, int n_in,
                              void* d_out, int out_size, void* d_ws, size_t ws_size,
                              hipStream_t stream) {
    const float* S  = (const float*)d_in[0];
    const float* ES = (const float*)d_in[1];
    const float* W1 = (const float*)d_in[2];
    const float* b1 = (const float*)d_in[3];
    const float* W2 = (const float*)d_in[4];
    const float* b2 = (const float*)d_in[5];

    short* ENT   = (short*)d_ws;                         // 28*2097152 shorts = 117.4 MB
    short* wsW1T = ENT + (size_t)P_ * 2097152;           // 3.67 MB
    short* wsW2T = wsW1T + (size_t)P_ * 65536;           // 3.67 MB (total 124.8 MB)

    float* OUT  = (float*)d_out;                         // updated [L,B,D]
    float* MEAS = OUT + (size_t)L_ * B_ * D_;            // measures [P,B]

    transpose_w<<<dim3(P_ * 64, 2), 256, 0, stream>>>(W1, W2, wsW1T, wsW2T);
    pair_mlp<<<dim3(B_ / 128, P_), 256, 0, stream>>>(S, ES, wsW1T, b1, wsW2T, b2, ENT);
    finalize<<<dim3((L_ * B_ * D_ / 8) / 256), 256, 0, stream>>>(S, ENT, OUT);
    fill_meas<<<dim3((P_ * B_ + 255) / 256), 256, 0, stream>>>(MEAS);
}

// Round 4
// 280.188 us; speedup vs baseline: 1.3925x; 1.3735x over previous
//
#include <hip/hip_runtime.h>
#include <math.h>

#define L_ 8
#define D_ 128
#define B_ 8192
#define P_ 28
#define ALPHA_ 0.1f

typedef __attribute__((ext_vector_type(8))) short bf16x8;
typedef __attribute__((ext_vector_type(4))) float f32x4;
union BF8 { int4 i; bf16x8 h; short s[8]; };

__device__ __forceinline__ short f2bf(float f) {
    unsigned u = __float_as_uint(f);
    unsigned r = (u + 0x7fffu + ((u >> 16) & 1u)) >> 16;   // RNE
    return (short)(r & 0xffffu);
}
__device__ __forceinline__ float bf2f(unsigned short s) {
    return __uint_as_float(((unsigned)s) << 16);
}
__device__ __forceinline__ unsigned rne2(float a, float b) {
    unsigned ua = __float_as_uint(a); ua += 0x7fffu + ((ua >> 16) & 1u);
    unsigned ub = __float_as_uint(b); ub += 0x7fffu + ((ub >> 16) & 1u);
    return __builtin_amdgcn_perm(ub, ua, 0x07060302);      // {b_hi16, a_hi16}
}

typedef const unsigned int __attribute__((address_space(1)))* gas_t;
typedef unsigned int __attribute__((address_space(3)))* las_t;

// W layout (both W1T/W2T), per (p,ch): [kb 8][ct 8][m 16][kk 32] bf16 = 64 KB.
// B-frag read (kb,ct): lanes (m,q) -> 1 KB contiguous.
__global__ void transpose_w(const float* __restrict__ W1, const float* __restrict__ W2,
                            short* __restrict__ T1, short* __restrict__ T2) {
    const float* W = blockIdx.y ? W2 : W1;
    short* T = blockIdx.y ? T2 : T1;
    const int p = blockIdx.x >> 3, kb = blockIdx.x & 7;
    __shared__ float tile[32][260];
    const int tid = threadIdx.x;
    for (int s = tid; s < 8192; s += 256) {
        int kk = s >> 8, n = s & 255;
        tile[kk][n] = W[((size_t)p * 256 + kb * 32 + kk) * 256 + n];
    }
    __syncthreads();
    const int n = tid;
    const int ch = n >> 7, ct = (n >> 4) & 7, mm = n & 15;
    const size_t ob = (((size_t)(p * 2 + ch) * 64) + kb * 8 + ct) * 512 + mm * 32;
    short tmp[32];
#pragma unroll
    for (int kk = 0; kk < 32; ++kk) tmp[kk] = f2bf(tile[kk][n]);
#pragma unroll
    for (int c4 = 0; c4 < 4; ++c4) {
        BF8 u;
#pragma unroll
        for (int e = 0; e < 8; ++e) u.s[e] = tmp[c4 * 8 + e];
        *(int4*)&T[ob + c4 * 8] = u.i;
    }
}

// H/ENT phase-local fragment layout per pair (1,048,576 shorts):
// elem(row, n) at ((rg*8 + n/32)<<9) + (row%16)*32 + n%32, rg = row/16 (row 0..4095)

// G1: h = tanh(comb @ W1 + b1) for one (pair, col-half), 256 rows.
// Weights LDS-resident (one barrier), rt=4 waves, no steady-state barriers.
__launch_bounds__(256, 2)
__global__ void gemm1(const float* __restrict__ S, const short* __restrict__ W1T,
                      const float* __restrict__ b1, short* __restrict__ H, int b0) {
    __shared__ short Wl[32768];                 // 64 KB
    const int pch = blockIdx.y;
    const int p = pch >> 1, ch = pch & 1;
    const int tid = threadIdx.x, lane = tid & 63, w = tid >> 6;
    const int m = lane & 15, q = lane >> 4;

    const short* wg = W1T + (size_t)pch * 32768;
#pragma unroll
    for (int r = 0; r < 16; ++r) {
        int u0 = w * 1024 + r * 64;             // 16-B units
        __builtin_amdgcn_global_load_lds((gas_t)(const void*)(wg + (size_t)(u0 + lane) * 8),
                                         (las_t)(void*)(Wl + (size_t)u0 * 8), 16, 0, 0);
    }

    int i = 0, base = 0;
    while (p >= base + (L_ - 1 - i)) { base += L_ - 1 - i; ++i; }
    const int j = i + 1 + (p - base);

    float bias[8];
#pragma unroll
    for (int ct = 0; ct < 8; ++ct) bias[ct] = b1[p * 256 + ch * 128 + ct * 16 + m];

    const int rwl = blockIdx.x * 256 + w * 64;  // phase-local wave row base
    const float* Si = S + ((size_t)i * B_ + b0 + rwl) * D_;
    const float* Sj = S + ((size_t)j * B_ + b0 + rwl) * D_;

    f32x4 acc[4][8];
#pragma unroll
    for (int rt = 0; rt < 4; ++rt)
#pragma unroll
        for (int ct = 0; ct < 8; ++ct) acc[rt][ct] = (f32x4){0.f, 0.f, 0.f, 0.f};

    __syncthreads();                            // weights ready (only barrier)

#pragma unroll
    for (int kb = 0; kb < 8; ++kb) {
        const float* Sl = (kb < 4) ? Si : Sj;
        const int col = (kb & 3) * 32 + q * 8;
        bf16x8 AF[4];
#pragma unroll
        for (int rt = 0; rt < 4; ++rt) {
            const float* src = Sl + (size_t)(rt * 16 + m) * D_ + col;
            float4 lo = *(const float4*)src;
            float4 hi = *(const float4*)(src + 4);
            BF8 u;
            u.i.x = rne2(lo.x, lo.y); u.i.y = rne2(lo.z, lo.w);
            u.i.z = rne2(hi.x, hi.y); u.i.w = rne2(hi.z, hi.w);
            AF[rt] = u.h;
        }
#pragma unroll
        for (int ct = 0; ct < 8; ++ct) {
            bf16x8 bfb = *(const bf16x8*)&Wl[((kb * 8 + ct) * 16 + m) * 32 + q * 8];
#pragma unroll
            for (int rt = 0; rt < 4; ++rt)
                acc[rt][ct] = __builtin_amdgcn_mfma_f32_16x16x32_bf16(AF[rt], bfb, acc[rt][ct], 0, 0, 0);
        }
    }

    // epilogue: tanh -> fragment-blocked H
    short* Hp = H + (size_t)p * 1048576;
#pragma unroll
    for (int rt = 0; rt < 4; ++rt) {
        const int rg = (rwl >> 4) + rt;
#pragma unroll
        for (int ct = 0; ct < 8; ++ct) {
            const int kd = ch * 4 + (ct >> 1);
            const int kk = (ct & 1) * 16 + m;
            const size_t eb = ((size_t)(rg * 8 + kd) << 9) + q * 128 + kk;
#pragma unroll
            for (int rr = 0; rr < 4; ++rr) {
                float x = acc[rt][ct][rr] + bias[ct];
                float e = exp2f(x * 2.885390081777927f);        // e^{2x}
                Hp[eb + rr * 32] = f2bf(1.f - 2.f * __builtin_amdgcn_rcpf(e + 1.f));
            }
        }
    }
}

// G2: ent = sigmoid(es)*(h @ W2 + b2), same structure; A from H (1 KB-contig frags)
__launch_bounds__(256, 2)
__global__ void gemm2(const float* __restrict__ ES, const short* __restrict__ W2T,
                      const float* __restrict__ b2, const short* __restrict__ H,
                      short* __restrict__ ENT) {
    __shared__ short Wl[32768];
    const int pch = blockIdx.y;
    const int p = pch >> 1, ch = pch & 1;
    const int tid = threadIdx.x, lane = tid & 63, w = tid >> 6;
    const int m = lane & 15, q = lane >> 4;

    const short* wg = W2T + (size_t)pch * 32768;
#pragma unroll
    for (int r = 0; r < 16; ++r) {
        int u0 = w * 1024 + r * 64;
        __builtin_amdgcn_global_load_lds((gas_t)(const void*)(wg + (size_t)(u0 + lane) * 8),
                                         (las_t)(void*)(Wl + (size_t)u0 * 8), 16, 0, 0);
    }

    int i = 0, base = 0;
    while (p >= base + (L_ - 1 - i)) { base += L_ - 1 - i; ++i; }
    const int j = i + 1 + (p - base);
    const float es = ES[i * L_ + j];
    const float st = 1.f / (1.f + expf(-es));

    float bias[8];
#pragma unroll
    for (int ct = 0; ct < 8; ++ct) bias[ct] = b2[p * 256 + ch * 128 + ct * 16 + m];

    const int rwl = blockIdx.x * 256 + w * 64;
    const int rgw = rwl >> 4;
    const short* Hp = H + (size_t)p * 1048576;

    f32x4 acc[4][8];
#pragma unroll
    for (int rt = 0; rt < 4; ++rt)
#pragma unroll
        for (int ct = 0; ct < 8; ++ct) acc[rt][ct] = (f32x4){0.f, 0.f, 0.f, 0.f};

    __syncthreads();

#pragma unroll
    for (int kb = 0; kb < 8; ++kb) {
        bf16x8 AF[4];
#pragma unroll
        for (int rt = 0; rt < 4; ++rt)
            AF[rt] = *(const bf16x8*)&Hp[(((size_t)(rgw + rt) * 8 + kb) << 9) + m * 32 + q * 8];
#pragma unroll
        for (int ct = 0; ct < 8; ++ct) {
            bf16x8 bfb = *(const bf16x8*)&Wl[((kb * 8 + ct) * 16 + m) * 32 + q * 8];
#pragma unroll
            for (int rt = 0; rt < 4; ++rt)
                acc[rt][ct] = __builtin_amdgcn_mfma_f32_16x16x32_bf16(AF[rt], bfb, acc[rt][ct], 0, 0, 0);
        }
    }

    short* Ep = ENT + (size_t)p * 1048576;
#pragma unroll
    for (int rt = 0; rt < 4; ++rt) {
        const int rg = rgw + rt;
#pragma unroll
        for (int ct = 0; ct < 8; ++ct) {
            const int kd = ch * 4 + (ct >> 1);
            const int kk = (ct & 1) * 16 + m;
            const size_t eb = ((size_t)(rg * 8 + kd) << 9) + q * 128 + kk;
#pragma unroll
            for (int rr = 0; rr < 4; ++rr)
                Ep[eb + rr * 32] = f2bf(st * (acc[rt][ct][rr] + bias[ct]));
        }
    }
}

// finalize (per phase): u <- u + alpha*(ent_part - u) in global pair order.
__global__ void finalize(const float* __restrict__ S, const short* __restrict__ ENT,
                         float* __restrict__ OUT, int b0) {
    const int idx = blockIdx.x * 256 + threadIdx.x;     // 524288 per phase
    const int k = idx >> 16;
    const int rem = idx & 65535;
    const int bl = rem >> 4;                            // 0..4095 phase-local row
    const int d0 = (rem & 15) * 8;
    const size_t sOff = ((size_t)k * B_ + b0 + bl) * D_ + d0;
    float4 u0 = *(const float4*)&S[sOff];
    float4 u1 = *(const float4*)&S[sOff + 4];
    float u[8] = {u0.x, u0.y, u0.z, u0.w, u1.x, u1.y, u1.z, u1.w};
    const int rg = bl >> 4, r16 = bl & 15;
    int p = 0;
#pragma unroll
    for (int i2 = 0; i2 < L_; ++i2) {
#pragma unroll
        for (int j2 = i2 + 1; j2 < L_; ++j2) {
            if (i2 == k || j2 == k) {
                const int side = (i2 == k) ? 0 : 1;
                const int kd = side * 4 + (d0 >> 5);
                const unsigned short* e = (const unsigned short*)ENT + (size_t)p * 1048576
                    + (((size_t)(rg * 8 + kd)) << 9) + r16 * 32 + (d0 & 31);
                ushort4 a = *(const ushort4*)e;
                ushort4 c = *(const ushort4*)(e + 4);
                u[0] += ALPHA_ * (bf2f(a.x) - u[0]);
                u[1] += ALPHA_ * (bf2f(a.y) - u[1]);
                u[2] += ALPHA_ * (bf2f(a.z) - u[2]);
                u[3] += ALPHA_ * (bf2f(a.w) - u[3]);
                u[4] += ALPHA_ * (bf2f(c.x) - u[4]);
                u[5] += ALPHA_ * (bf2f(c.y) - u[5]);
                u[6] += ALPHA_ * (bf2f(c.z) - u[6]);
                u[7] += ALPHA_ * (bf2f(c.w) - u[7]);
            }
            ++p;
        }
    }
    *(float4*)&OUT[sOff]     = (float4){u[0], u[1], u[2], u[3]};
    *(float4*)&OUT[sOff + 4] = (float4){u[4], u[5], u[6], u[7]};
}

// measures analytically constant (lam1 == 1 after normalize):
// (127+127-255)*1e-12*(-ln 1e-12) = -2.7631021115928547e-11
__global__ void fill_meas(float* __restrict__ M) {
    int t = blockIdx.x * 256 + threadIdx.x;
    if (t < P_ * B_) M[t] = -2.7631021115928547e-11f;
}

extern "C" void kernel_launch(void* const* d_in, const int* in_sizes, int n_in,
                              void* d_out, int out_size, void* d_ws, size_t ws_size,
                              hipStream_t stream) {
    const float* S  = (const float*)d_in[0];
    const float* ES = (const float*)d_in[1];
    const float* W1 = (const float*)d_in[2];
    const float* b1 = (const float*)d_in[3];
    const float* W2 = (const float*)d_in[4];
    const float* b2 = (const float*)d_in[5];

    short* H   = (short*)d_ws;                 // 28*1048576 shorts = 58.7 MB (half-B)
    short* ENT = H   + (size_t)P_ * 1048576;   // 58.7 MB
    short* T1  = ENT + (size_t)P_ * 1048576;   // 3.67 MB
    short* T2  = T1  + (size_t)P_ * 65536;     // 3.67 MB  (total = 124,780,544 B, proven)

    float* OUT  = (float*)d_out;               // updated [L,B,D]
    float* MEAS = OUT + (size_t)L_ * B_ * D_;  // measures [P,B]

    transpose_w<<<dim3(P_ * 8, 2), 256, 0, stream>>>(W1, W2, T1, T2);
    for (int ph = 0; ph < 2; ++ph) {
        const int b0 = ph * 4096;
        gemm1<<<dim3(16, P_ * 2), 256, 0, stream>>>(S, T1, b1, H, b0);
        gemm2<<<dim3(16, P_ * 2), 256, 0, stream>>>(ES, T2, b2, H, ENT);
        finalize<<<dim3(2048), 256, 0, stream>>>(S, ENT, OUT, b0);
    }
    fill_meas<<<dim3(896), 256, 0, stream>>>(MEAS);
}